// Round 7
// baseline (384.514 us; speedup 1.0000x reference)
//
#include <hip/hip_runtime.h>
#include <stdint.h>

#define BT_ 16384   // B*T
#define TT  1024
#define CHUNKS 32
#define CLEN   32
#define LANES  16384  // E*B*D

typedef __bf16 bf16x8 __attribute__((ext_vector_type(8)));
typedef float  f32x4  __attribute__((ext_vector_type(4)));
typedef unsigned int u32x4 __attribute__((ext_vector_type(4)));
typedef unsigned short u16;

__device__ __forceinline__ float b2f(u16 s){
    union { float f; unsigned int u; } c; c.u = ((unsigned int)s) << 16; return c.f;
}
__device__ __forceinline__ u16 f2b(float f){
    union { float f; unsigned int u; } c; c.f = f;
    unsigned int u = c.u;
    return (u16)((u + 0x7fffu + ((u >> 16) & 1u)) >> 16);
}

// async global->LDS, 16 B per lane; LDS dest is wave-uniform base + lane*16
__device__ __forceinline__ void gload_lds16(const u16* g, u16* lds){
    __builtin_amdgcn_global_load_lds(
        (const __attribute__((address_space(1))) void*)g,
        (__attribute__((address_space(3))) void*)lds, 16, 0, 0);
}

// ---------------------------------------------------------------------------
// x: fp32 -> bf16 (A operand of in_proj)
// ---------------------------------------------------------------------------
__global__ __launch_bounds__(256) void conv_k(const float* __restrict__ x, u16* __restrict__ xc)
{
    long i = (long)blockIdx.x * 256 + threadIdx.x;   // < 4,194,304
    xc[i] = f2b(x[i]);
}

// ---------------------------------------------------------------------------
// Weight prep: fp32 -> bf16, TRANSPOSED to [n][k].
// 28 source matrices of 256x256 ([i][o], o contiguous):
//   w in [0,12)  : in_proj (z=k3*4+e)      -> c_ipw_t + w*65536          , ostride 256
//   w in [12,20) : mid (c=(w-12)>>2,e=&3)  -> buf_mw_t + e*131072 + c*256, ostride 512, sign -1 for c=1
//   w in [20,24) : ff_w1 (e)               -> c_fw1_t + e*65536          , ostride 256
//   w in [24,28) : ff_w2 (e)               -> c_fw2_t + e*65536          , ostride 256
// ---------------------------------------------------------------------------
__global__ __launch_bounds__(256) void prep_w(
    const float* __restrict__ ipw, const float* __restrict__ mw,
    const float* __restrict__ fw1, const float* __restrict__ fw2,
    u16* __restrict__ d_ipw, u16* __restrict__ d_mw,
    u16* __restrict__ d_fw1, u16* __restrict__ d_fw2)
{
    __shared__ u16 tile[64][72];
    int blk = blockIdx.x;            // < 448
    int w = blk >> 4, t = blk & 15;
    int tr = (t >> 2) * 64;          // i origin
    int tc = (t & 3) * 64;           // o origin
    const float* src; u16* dst; int ostride; float sign = 1.f;
    if (w < 12)      { src = ipw + (size_t)w * 65536; dst = d_ipw + (size_t)w * 65536; ostride = 256; }
    else if (w < 20) { int u = w - 12, c = u >> 2, e = u & 3;
                       src = mw + (size_t)u * 65536;
                       dst = d_mw + (size_t)e * 131072 + c * 256; ostride = 512;
                       if (c) sign = -1.f; }
    else if (w < 24) { int e = w - 20; src = fw1 + (size_t)e * 65536; dst = d_fw1 + (size_t)e * 65536; ostride = 256; }
    else             { int e = w - 24; src = fw2 + (size_t)e * 65536; dst = d_fw2 + (size_t)e * 65536; ostride = 256; }

    int q = threadIdx.x;
    int r = q >> 2, cb = (q & 3) * 16;
#pragma unroll
    for (int j = 0; j < 4; j++) {
        int col = cb + j * 4;
        const float4 v = *reinterpret_cast<const float4*>(src + (size_t)(tr + r) * 256 + tc + col);
        tile[r][col + 0] = f2b(v.x * sign);
        tile[r][col + 1] = f2b(v.y * sign);
        tile[r][col + 2] = f2b(v.z * sign);
        tile[r][col + 3] = f2b(v.w * sign);
    }
    __syncthreads();
    int ol = q >> 2, ib = (q & 3) * 16;
    union { u16 s[8]; u32x4 v; } p0, p1;
#pragma unroll
    for (int k = 0; k < 8; k++) { p0.s[k] = tile[ib + k][ol]; p1.s[k] = tile[ib + 8 + k][ol]; }
    u16* drow = dst + (size_t)(tc + ol) * ostride + tr + ib;
    *reinterpret_cast<u32x4*>(drow)     = p0.v;
    *reinterpret_cast<u32x4*>(drow + 8) = p1.v;
}

// ---------------------------------------------------------------------------
// Barrier-free-K GEMM: C[M=16384 x N=256] = A[M x K] * B^T[N x K].
// Per block: B panel (128 cols x 256 K) resident in LDS (loaded once per
// 256-K half via global_load_lds, chunk-swizzled phys = c ^ (row&7));
// A fragments stream global->VGPR directly (no LDS, no barriers in K-loop).
// Each wave: 32 rows x 128 cols, acc[2][8] (64 VGPRs).
// mode 1: in_proj  z=(k3*4+e): k3<2 -> out0 interleaved *gamma +bias ; k3==2 -> out1 plain +bias
// mode 2: mid      z=e: + (mid_b0-mid_b1) + aux(o) -> out0
// mode 3: ff1      z=e: +bias, exact gelu -> out0
// mode 4: ff2      z=e: +bias + aux(residual) -> out0
// ---------------------------------------------------------------------------
__global__ __launch_bounds__(256, 2) void gemm_k(
    const u16* __restrict__ A0, const u16* __restrict__ B0,
    const float* __restrict__ biasf, const u16* __restrict__ aux,
    const float* __restrict__ gamlogf, u16* __restrict__ out0,
    u16* __restrict__ out1, int K, int mode)
{
    __shared__ __align__(16) u16 Bs[128 * 256];   // [n][k-half], swizzled 16B chunks

    int tid  = threadIdx.x;
    int wave = tid >> 6, lane = tid & 63;
    int quad = lane >> 4, l16 = lane & 15;
    int m0 = blockIdx.x * 128, n0 = blockIdx.y * 128;
    int z = blockIdx.z;
    int e, k3 = 0;
    const u16* A;
    const u16* Bm;
    if (mode == 1) { k3 = z >> 2; e = z & 3; A = A0; }
    else           { e = z; A = A0 + (size_t)e * BT_ * K; }
    Bm = B0 + (size_t)(mode == 1 ? z : e) * 256 * K;

    f32x4 acc[2][8];
#pragma unroll
    for (int i = 0; i < 2; i++)
#pragma unroll
        for (int j = 0; j < 8; j++) acc[i][j] = (f32x4){0.f, 0.f, 0.f, 0.f};

    int sr = lane >> 5, ss = lane & 31;    // staging: 2 rows x 32 chunks per instr
    int nhalf = K >> 8;                    // 1 (K=256) or 2 (K=512)

    for (int kh = 0; kh <= nhalf - 1 || kh == 0; kh++) {
        if (kh) __syncthreads();           // all waves done reading previous half
        // stage B panel half: wave covers rows [wave*32, wave*32+32)
#pragma unroll
        for (int i = 0; i < 16; i++) {
            int row = wave * 32 + i * 2 + sr;
            int c = ss ^ (row & 7);
            gload_lds16(Bm + (size_t)(n0 + row) * K + kh * 256 + c * 8,
                        &Bs[(wave * 32 + i * 2) * 256]);
        }
        __syncthreads();                   // also drains the staging DMA (vmcnt 0)

        const u16* Arow0 = A + (size_t)(m0 + wave * 32 + l16) * K + kh * 256 + quad * 8;
        const u16* Arow1 = Arow0 + (size_t)16 * K;

#pragma unroll
        for (int kt = 0; kt < 8; kt++) {
            bf16x8 a0, a1;
            { union { u32x4 v; bf16x8 b; } u; u.v = *reinterpret_cast<const u32x4*>(Arow0 + kt * 32); a0 = u.b; }
            { union { u32x4 v; bf16x8 b; } u; u.v = *reinterpret_cast<const u32x4*>(Arow1 + kt * 32); a1 = u.b; }
#pragma unroll
            for (int nf = 0; nf < 8; nf++) {
                int row = nf * 16 + l16;
                int c = (kt * 4 + quad) ^ (row & 7);
                union { u32x4 v; bf16x8 b; } u;
                u.v = *reinterpret_cast<const u32x4*>(&Bs[row * 256 + c * 8]);
                acc[0][nf] = __builtin_amdgcn_mfma_f32_16x16x32_bf16(a0, u.b, acc[0][nf], 0, 0, 0);
                acc[1][nf] = __builtin_amdgcn_mfma_f32_16x16x32_bf16(a1, u.b, acc[1][nf], 0, 0, 0);
            }
        }
        if (kh == nhalf - 1) break;
    }

    // epilogue: hoist per-column quantities (col depends only on nf)
    float bias_nf[8], gam_nf[8];
#pragma unroll
    for (int nf = 0; nf < 8; nf++) {
        int col = n0 + nf * 16 + l16;
        if (mode == 1) {
            bias_nf[nf] = biasf[z * 256 + col];
            gam_nf[nf] = (k3 < 2) ? expf(gamlogf[2048 + e * 256 + col]) : 1.f;
        } else if (mode == 2) {
            bias_nf[nf] = biasf[e * 256 + col] - biasf[1024 + e * 256 + col];
        } else {
            bias_nf[nf] = biasf[e * 256 + col];
        }
    }

#pragma unroll
    for (int mf = 0; mf < 2; mf++) {
#pragma unroll
        for (int nf = 0; nf < 8; nf++) {
            int col = n0 + nf * 16 + l16;
#pragma unroll
            for (int r = 0; r < 4; r++) {
                int row = m0 + wave * 32 + mf * 16 + quad * 4 + r;
                float v = acc[mf][nf][r] + bias_nf[nf];
                size_t pidx = ((size_t)e * BT_ + row) * 256 + col;
                if (mode == 1) {
                    if (k3 < 2) {
                        out0[((size_t)(e * BT_ + row) * 2 + k3) * 256 + col] = f2b(v * gam_nf[nf]);
                    } else {
                        out1[pidx] = f2b(v);
                    }
                } else if (mode == 2) {
                    out0[pidx] = f2b(v + b2f(aux[pidx]));
                } else if (mode == 3) {
                    v = 0.5f * v * (1.0f + erff(v * 0.70710678118654752f));
                    out0[pidx] = f2b(v);
                } else {
                    out0[pidx] = f2b(v + b2f(aux[pidx]));
                }
            }
        }
    }
}

// ---------------------------------------------------------------------------
// LRU scan, 3 phases, 2 d-lanes per thread (u32 loads/stores).
// buf_u layout: ((e*BT + b*T + t)*2 + c)*256 + d  (c=0:re, 1:im)
// ---------------------------------------------------------------------------
__global__ __launch_bounds__(256) void scan_a(const u16* __restrict__ u,
    const float* __restrict__ plog, float2* __restrict__ carry)
{
    int l2 = blockIdx.x * 256 + threadIdx.x;      // < 8192
    int chunk = blockIdx.y;
    int dd = (l2 & 127) * 2, b = (l2 >> 7) & 15, e = l2 >> 11;
    float nu0 = expf(plog[e * 256 + dd]),        nu1 = expf(plog[e * 256 + dd + 1]);
    float th0 = expf(plog[1024 + e * 256 + dd]), th1 = expf(plog[1024 + e * 256 + dd + 1]);
    float m0 = expf(-nu0), m1 = expf(-nu1);
    float fr0 = m0 * cosf(th0), fi0 = m0 * sinf(th0);
    float fr1 = m1 * cosf(th1), fi1 = m1 * sinf(th1);
    size_t base = ((size_t)e * BT_ + b * TT) * 512 + (size_t)chunk * CLEN * 512 + dd;
    float hr0 = 0.f, hi0 = 0.f, hr1 = 0.f, hi1 = 0.f;
    for (int t = 0; t < CLEN; t++) {
        unsigned int wr = *reinterpret_cast<const unsigned int*>(u + base);
        unsigned int wi = *reinterpret_cast<const unsigned int*>(u + base + 256);
        float ur0 = b2f((u16)wr), ur1 = b2f((u16)(wr >> 16));
        float ui0 = b2f((u16)wi), ui1 = b2f((u16)(wi >> 16));
        float a0 = fr0 * hr0 - fi0 * hi0 + ur0;
        float b0 = fr0 * hi0 + fi0 * hr0 + ui0;
        float a1 = fr1 * hr1 - fi1 * hi1 + ur1;
        float b1 = fr1 * hi1 + fi1 * hr1 + ui1;
        hr0 = a0; hi0 = b0; hr1 = a1; hi1 = b1;
        base += 512;
    }
    size_t ci = (size_t)chunk * LANES + (size_t)e * 4096 + b * 256 + dd;
    *reinterpret_cast<float4*>(&carry[ci]) = make_float4(hr0, hi0, hr1, hi1);
}

__global__ __launch_bounds__(256) void scan_b(const float* __restrict__ plog,
                                              float2* __restrict__ carry)
{
    int l = blockIdx.x * 256 + threadIdx.x;
    int d = l & 255, e = l >> 12;
    float nu = expf(plog[e * 256 + d]);
    float th = expf(plog[1024 + e * 256 + d]);
    float magL = expf(-nu * (float)CLEN);
    float ang = th * (float)CLEN;
    float frL = magL * cosf(ang), fiL = magL * sinf(ang);
    float gr = 0.f, gi = 0.f;
    for (int j = 0; j < CHUNKS; j++) {
        float2 c = carry[(size_t)j * LANES + l];
        carry[(size_t)j * LANES + l] = make_float2(gr, gi);
        float gr2 = frL * gr - fiL * gi + c.x;
        float gi2 = frL * gi + fiL * gr + c.y;
        gr = gr2; gi = gi2;
    }
}

// scan_c also writes hidden (fp32, exact) on the last chunk.
__global__ __launch_bounds__(256) void scan_c(u16* __restrict__ u,
    const float* __restrict__ plog, const float2* __restrict__ carry,
    float* __restrict__ outh)
{
    int l2 = blockIdx.x * 256 + threadIdx.x;      // < 8192
    int chunk = blockIdx.y;
    int dd = (l2 & 127) * 2, b = (l2 >> 7) & 15, e = l2 >> 11;
    float nu0 = expf(plog[e * 256 + dd]),        nu1 = expf(plog[e * 256 + dd + 1]);
    float th0 = expf(plog[1024 + e * 256 + dd]), th1 = expf(plog[1024 + e * 256 + dd + 1]);
    float m0 = expf(-nu0), m1 = expf(-nu1);
    float fr0 = m0 * cosf(th0), fi0 = m0 * sinf(th0);
    float fr1 = m1 * cosf(th1), fi1 = m1 * sinf(th1);
    size_t base = ((size_t)e * BT_ + b * TT) * 512 + (size_t)chunk * CLEN * 512 + dd;
    size_t ci = (size_t)chunk * LANES + (size_t)e * 4096 + b * 256 + dd;
    float4 c0 = *reinterpret_cast<const float4*>(&carry[ci]);
    float hr0 = c0.x, hi0 = c0.y, hr1 = c0.z, hi1 = c0.w;
    for (int t = 0; t < CLEN; t++) {
        unsigned int wr = *reinterpret_cast<const unsigned int*>(u + base);
        unsigned int wi = *reinterpret_cast<const unsigned int*>(u + base + 256);
        float ur0 = b2f((u16)wr), ur1 = b2f((u16)(wr >> 16));
        float ui0 = b2f((u16)wi), ui1 = b2f((u16)(wi >> 16));
        float a0 = fr0 * hr0 - fi0 * hi0 + ur0;
        float b0 = fr0 * hi0 + fi0 * hr0 + ui0;
        float a1 = fr1 * hr1 - fi1 * hi1 + ur1;
        float b1 = fr1 * hi1 + fi1 * hr1 + ui1;
        hr0 = a0; hi0 = b0; hr1 = a1; hi1 = b1;
        *reinterpret_cast<unsigned int*>(u + base) =
            (unsigned int)f2b(hr0) | ((unsigned int)f2b(hr1) << 16);
        *reinterpret_cast<unsigned int*>(u + base + 256) =
            (unsigned int)f2b(hi0) | ((unsigned int)f2b(hi1) << 16);
        base += 512;
    }
    if (chunk == CHUNKS - 1) {
        float* oh = outh + (size_t)4 * BT_ * 256;
        *reinterpret_cast<float2*>(&oh[b * 2048 + e * 256 + dd])        = make_float2(hr0, hr1);
        *reinterpret_cast<float2*>(&oh[b * 2048 + 1024 + e * 256 + dd]) = make_float2(hi0, hi1);
    }
}

// LayerNorm across (e,d) per row r=(b,t); h2 plain (E, BT, D) bf16; fp32 out
__global__ __launch_bounds__(256) void ln_k(const u16* __restrict__ h2,
    const float* __restrict__ lnw, const float* __restrict__ lnb,
    float* __restrict__ out)
{
    int r = blockIdx.x;
    int d = threadIdx.x;
    float v[4]; float s1 = 0.f, s2 = 0.f;
#pragma unroll
    for (int e = 0; e < 4; e++) {
        float x = b2f(h2[((size_t)e * BT_ + r) * 256 + d]);
        v[e] = x; s1 += x; s2 += x * x;
    }
#pragma unroll
    for (int off = 32; off; off >>= 1) {
        s1 += __shfl_down(s1, off, 64);
        s2 += __shfl_down(s2, off, 64);
    }
    __shared__ float sm[8];
    int wave = threadIdx.x >> 6, lane = threadIdx.x & 63;
    if (lane == 0) { sm[wave] = s1; sm[4 + wave] = s2; }
    __syncthreads();
    float S1 = sm[0] + sm[1] + sm[2] + sm[3];
    float S2 = sm[4] + sm[5] + sm[6] + sm[7];
    float mean = S1 * (1.0f / 1024.0f);
    float var = S2 * (1.0f / 1024.0f) - mean * mean;
    float rstd = rsqrtf(var + 1e-5f);
#pragma unroll
    for (int e = 0; e < 4; e++) {
        float o = (v[e] - mean) * rstd * lnw[e * 256 + d] + lnb[e * 256 + d];
        out[((size_t)e * BT_ + r) * 256 + d] = o;
    }
}

extern "C" void kernel_launch(void* const* d_in, const int* in_sizes, int n_in,
                              void* d_out, int out_size, void* d_ws, size_t ws_size,
                              hipStream_t stream)
{
    const float* x    = (const float*)d_in[0];
    const float* ipw  = (const float*)d_in[1];
    const float* ipb  = (const float*)d_in[2];
    const float* plog = (const float*)d_in[3];
    const float* mw   = (const float*)d_in[4];
    const float* mb   = (const float*)d_in[5];
    const float* fw1  = (const float*)d_in[6];
    const float* fb1  = (const float*)d_in[7];
    const float* fw2  = (const float*)d_in[8];
    const float* fb2  = (const float*)d_in[9];
    const float* lnw  = (const float*)d_in[10];
    const float* lnb  = (const float*)d_in[11];
    float* out = (float*)d_out;

    // Workspace (u16 elem offsets; ~99.5 MiB):
    //   buf_u    [0,          33,554,432)  scan buffer (E,BT,2,D) bf16, later h2
    //   buf_out  [33,554,432, 50,331,648)  mid output bf16; ALIASED early by:
    //              xc (bf16 x, 4,194,304) at 33,554,432   [dead after in_proj]
    //              carry (float2, 4 MiB)  at 37,748,736   [dead after scan_c]
    //   buf_mw_t [50,331,648, 50,855,936)  [e][o][c*256+d] stacked, sign-folded
    //   c_ipw_t  [50,855,936, 51,642,368)  [z][o][i]
    //   c_fw1_t  [51,642,368, 51,904,512)  [e][o][d]
    //   c_fw2_t  [51,904,512, 52,166,656)  [e][o][d]
    // d_out bytes [0, 33.5 MB) double as bf16 scratch for `o` then `h1`.
    u16* W = (u16*)d_ws;
    u16* buf_u    = W;
    u16* buf_out  = W + (size_t)33554432;
    u16* xc       = W + (size_t)33554432;
    float2* carry = (float2*)(W + (size_t)37748736);
    u16* buf_mw_t = W + (size_t)50331648;
    u16* c_ipw_t  = W + (size_t)50855936;
    u16* c_fw1_t  = W + (size_t)51642368;
    u16* c_fw2_t  = W + (size_t)51904512;
    u16* scratch  = (u16*)d_out;

    conv_k<<<16384, 256, 0, stream>>>(x, xc);
    prep_w<<<448, 256, 0, stream>>>(ipw, mw, fw1, fw2, c_ipw_t, buf_mw_t, c_fw1_t, c_fw2_t);
    // in_proj: u0,u1 (gamma-scaled, interleaved) -> buf_u ; o -> d_out scratch
    gemm_k<<<dim3(128, 2, 12), 256, 0, stream>>>(xc, c_ipw_t, ipb, nullptr, plog, buf_u, scratch, 256, 1);
    // LRU scan (chunked, 3 phases), in-place in buf_u (xc dead now); hidden fused into scan_c
    scan_a<<<dim3(32, CHUNKS), 256, 0, stream>>>(buf_u, plog, carry);
    scan_b<<<64, 256, 0, stream>>>(plog, carry);
    scan_c<<<dim3(32, CHUNKS), 256, 0, stream>>>(buf_u, plog, carry, out);
    // mid (K=512 fused r/i) + o -> buf_out   (carry dead now)
    gemm_k<<<dim3(128, 2, 4), 256, 0, stream>>>(buf_u, buf_mw_t, mb, scratch, nullptr, buf_out, nullptr, 512, 2);
    // ff1 + gelu -> d_out scratch (h1; `o` dead)
    gemm_k<<<dim3(128, 2, 4), 256, 0, stream>>>(buf_out, c_fw1_t, fb1, nullptr, nullptr, scratch, nullptr, 256, 3);
    // ff2 + residual -> buf_u (h2 plain; scan data dead)
    gemm_k<<<dim3(128, 2, 4), 256, 0, stream>>>(scratch, c_fw2_t, fb2, buf_out, nullptr, buf_u, nullptr, 256, 4);
    // layernorm across (e,d) -> d_out fp32 (overwrites scratch region last)
    ln_k<<<16384, 256, 0, stream>>>(buf_u, lnw, lnb, out);
}

// Round 8
// 367.025 us; speedup vs baseline: 1.0477x; 1.0477x over previous
//
#include <hip/hip_runtime.h>
#include <stdint.h>

#define BT_ 16384   // B*T
#define TT  1024
#define CHUNKS 32
#define CLEN   32
#define LANES  16384  // E*B*D

typedef __bf16 bf16x8 __attribute__((ext_vector_type(8)));
typedef float  f32x4  __attribute__((ext_vector_type(4)));
typedef unsigned int u32x4 __attribute__((ext_vector_type(4)));
typedef unsigned short u16;

__device__ __forceinline__ float b2f(u16 s){
    union { float f; unsigned int u; } c; c.u = ((unsigned int)s) << 16; return c.f;
}
__device__ __forceinline__ u16 f2b(float f){
    union { float f; unsigned int u; } c; c.f = f;
    unsigned int u = c.u;
    return (u16)((u + 0x7fffu + ((u >> 16) & 1u)) >> 16);
}

// async global->LDS, 16 B per lane; LDS dest is wave-uniform base + lane*16
__device__ __forceinline__ void gload_lds16(const u16* g, u16* lds){
    __builtin_amdgcn_global_load_lds(
        (const __attribute__((address_space(1))) void*)g,
        (__attribute__((address_space(3))) void*)lds, 16, 0, 0);
}

// ---------------------------------------------------------------------------
// x: fp32 -> bf16 (A operand of in_proj)
// ---------------------------------------------------------------------------
__global__ __launch_bounds__(256) void conv_k(const float* __restrict__ x, u16* __restrict__ xc)
{
    long i = (long)blockIdx.x * 256 + threadIdx.x;   // < 4,194,304
    xc[i] = f2b(x[i]);
}

// ---------------------------------------------------------------------------
// Weight prep: fp32 -> bf16, TRANSPOSED to [n][k].
// 28 source matrices of 256x256 ([i][o], o contiguous):
//   w in [0,12)  : in_proj (z=k3*4+e)      -> c_ipw_t + w*65536          , ostride 256
//   w in [12,20) : mid (c=(w-12)>>2,e=&3)  -> buf_mw_t + e*131072 + c*256, ostride 512, sign -1 for c=1
//   w in [20,24) : ff_w1 (e)               -> c_fw1_t + e*65536          , ostride 256
//   w in [24,28) : ff_w2 (e)               -> c_fw2_t + e*65536          , ostride 256
// ---------------------------------------------------------------------------
__global__ __launch_bounds__(256) void prep_w(
    const float* __restrict__ ipw, const float* __restrict__ mw,
    const float* __restrict__ fw1, const float* __restrict__ fw2,
    u16* __restrict__ d_ipw, u16* __restrict__ d_mw,
    u16* __restrict__ d_fw1, u16* __restrict__ d_fw2)
{
    __shared__ u16 tile[64][72];
    int blk = blockIdx.x;            // < 448
    int w = blk >> 4, t = blk & 15;
    int tr = (t >> 2) * 64;          // i origin
    int tc = (t & 3) * 64;           // o origin
    const float* src; u16* dst; int ostride; float sign = 1.f;
    if (w < 12)      { src = ipw + (size_t)w * 65536; dst = d_ipw + (size_t)w * 65536; ostride = 256; }
    else if (w < 20) { int u = w - 12, c = u >> 2, e = u & 3;
                       src = mw + (size_t)u * 65536;
                       dst = d_mw + (size_t)e * 131072 + c * 256; ostride = 512;
                       if (c) sign = -1.f; }
    else if (w < 24) { int e = w - 20; src = fw1 + (size_t)e * 65536; dst = d_fw1 + (size_t)e * 65536; ostride = 256; }
    else             { int e = w - 24; src = fw2 + (size_t)e * 65536; dst = d_fw2 + (size_t)e * 65536; ostride = 256; }

    int q = threadIdx.x;
    int r = q >> 2, cb = (q & 3) * 16;
#pragma unroll
    for (int j = 0; j < 4; j++) {
        int col = cb + j * 4;
        const float4 v = *reinterpret_cast<const float4*>(src + (size_t)(tr + r) * 256 + tc + col);
        tile[r][col + 0] = f2b(v.x * sign);
        tile[r][col + 1] = f2b(v.y * sign);
        tile[r][col + 2] = f2b(v.z * sign);
        tile[r][col + 3] = f2b(v.w * sign);
    }
    __syncthreads();
    int ol = q >> 2, ib = (q & 3) * 16;
    union { u16 s[8]; u32x4 v; } p0, p1;
#pragma unroll
    for (int k = 0; k < 8; k++) { p0.s[k] = tile[ib + k][ol]; p1.s[k] = tile[ib + 8 + k][ol]; }
    u16* drow = dst + (size_t)(tc + ol) * ostride + tr + ib;
    *reinterpret_cast<u32x4*>(drow)     = p0.v;
    *reinterpret_cast<u32x4*>(drow + 8) = p1.v;
}

// ---------------------------------------------------------------------------
// Barrier-free-K GEMM, small-LDS variant: C[16384 x 256] = A[M x K] * B^T[N x K].
// Block tile: 128 m x 64 n. B panel 64 x 256K = 32 KB LDS, loaded once per
// 256-K half (chunk-swizzled phys = c ^ (row&7)); zero barriers in K-loop.
// A streams global->VGPR with an explicit 1-deep kt pipeline.
// Wave: 32 m-rows (2 sets of 16) x 64 cols; acc[2][4] (32 VGPR).
// __launch_bounds__(256,4): VGPR<=128 -> 4 blocks/CU (LDS allows 5).
// mode 1: in_proj  z=(k3*4+e): k3<2 -> out0 interleaved *gamma +bias ; k3==2 -> out1 plain +bias
// mode 2: mid      z=e: + (mid_b0-mid_b1) + aux(o) -> out0
// mode 3: ff1      z=e: +bias, exact gelu -> out0
// mode 4: ff2      z=e: +bias + aux(residual) -> out0
// ---------------------------------------------------------------------------
__global__ __launch_bounds__(256, 4) void gemm_k(
    const u16* __restrict__ A0, const u16* __restrict__ B0,
    const float* __restrict__ biasf, const u16* __restrict__ aux,
    const float* __restrict__ gamlogf, u16* __restrict__ out0,
    u16* __restrict__ out1, int K, int mode)
{
    __shared__ __align__(16) u16 Bs[64 * 256];   // 32 KB, [n][k-half], swizzled 16B chunks

    int tid  = threadIdx.x;
    int wave = tid >> 6, lane = tid & 63;
    int quad = lane >> 4, l16 = lane & 15;
    int m0 = blockIdx.x * 128, n0 = blockIdx.y * 64;
    int z = blockIdx.z;
    int e, k3 = 0;
    const u16* A;
    const u16* Bm;
    if (mode == 1) { k3 = z >> 2; e = z & 3; A = A0; }
    else           { e = z; A = A0 + (size_t)e * BT_ * K; }
    Bm = B0 + (size_t)(mode == 1 ? z : e) * 256 * K;

    f32x4 acc[2][4];
#pragma unroll
    for (int i = 0; i < 2; i++)
#pragma unroll
        for (int j = 0; j < 4; j++) acc[i][j] = (f32x4){0.f, 0.f, 0.f, 0.f};

    int srow = lane >> 5, schunk = lane & 31;   // staging: 2 rows x 32 chunks / instr
    int nhalf = K >> 8;                          // 1 (K=256) or 2 (K=512)

    for (int kh = 0; kh < nhalf; kh++) {
        if (kh) __syncthreads();                 // waves done reading previous half
        // stage B panel half: wave covers panel rows [wave*16, wave*16+16)
#pragma unroll
        for (int i = 0; i < 8; i++) {
            int row = wave * 16 + i * 2 + srow;
            int c = schunk ^ (row & 7);
            gload_lds16(Bm + (size_t)(n0 + row) * K + kh * 256 + c * 8,
                        &Bs[(wave * 16 + i * 2) * 256]);
        }
        __syncthreads();                         // drains staging DMA (vmcnt 0)

        const u16* Arow0 = A + (size_t)(m0 + wave * 32 + l16) * K + kh * 256 + quad * 8;
        const u16* Arow1 = Arow0 + (size_t)16 * K;

        bf16x8 a0c, a1c, a0n, a1n;
        { union { u32x4 v; bf16x8 b; } u; u.v = *reinterpret_cast<const u32x4*>(Arow0); a0c = u.b; }
        { union { u32x4 v; bf16x8 b; } u; u.v = *reinterpret_cast<const u32x4*>(Arow1); a1c = u.b; }
#pragma unroll
        for (int kt = 0; kt < 8; kt++) {
            if (kt < 7) {
                union { u32x4 v; bf16x8 b; } u;
                u.v = *reinterpret_cast<const u32x4*>(Arow0 + (kt + 1) * 32); a0n = u.b;
                u.v = *reinterpret_cast<const u32x4*>(Arow1 + (kt + 1) * 32); a1n = u.b;
            }
#pragma unroll
            for (int nf = 0; nf < 4; nf++) {
                int row = nf * 16 + l16;
                int c = (kt * 4 + quad) ^ (row & 7);
                union { u32x4 v; bf16x8 b; } u;
                u.v = *reinterpret_cast<const u32x4*>(&Bs[row * 256 + c * 8]);
                acc[0][nf] = __builtin_amdgcn_mfma_f32_16x16x32_bf16(a0c, u.b, acc[0][nf], 0, 0, 0);
                acc[1][nf] = __builtin_amdgcn_mfma_f32_16x16x32_bf16(a1c, u.b, acc[1][nf], 0, 0, 0);
            }
            a0c = a0n; a1c = a1n;
        }
    }

    // epilogue: hoist per-column quantities (col depends only on nf)
    float bias_nf[4], gam_nf[4];
#pragma unroll
    for (int nf = 0; nf < 4; nf++) {
        int col = n0 + nf * 16 + l16;
        if (mode == 1) {
            bias_nf[nf] = biasf[z * 256 + col];
            gam_nf[nf] = (k3 < 2) ? expf(gamlogf[2048 + e * 256 + col]) : 1.f;
        } else if (mode == 2) {
            bias_nf[nf] = biasf[e * 256 + col] - biasf[1024 + e * 256 + col];
        } else {
            bias_nf[nf] = biasf[e * 256 + col];
        }
    }

#pragma unroll
    for (int mf = 0; mf < 2; mf++) {
#pragma unroll
        for (int nf = 0; nf < 4; nf++) {
            int col = n0 + nf * 16 + l16;
#pragma unroll
            for (int r = 0; r < 4; r++) {
                int row = m0 + wave * 32 + mf * 16 + quad * 4 + r;
                float v = acc[mf][nf][r] + bias_nf[nf];
                size_t pidx = ((size_t)e * BT_ + row) * 256 + col;
                if (mode == 1) {
                    if (k3 < 2) {
                        out0[((size_t)(e * BT_ + row) * 2 + k3) * 256 + col] = f2b(v * gam_nf[nf]);
                    } else {
                        out1[pidx] = f2b(v);
                    }
                } else if (mode == 2) {
                    out0[pidx] = f2b(v + b2f(aux[pidx]));
                } else if (mode == 3) {
                    v = 0.5f * v * (1.0f + erff(v * 0.70710678118654752f));
                    out0[pidx] = f2b(v);
                } else {
                    out0[pidx] = f2b(v + b2f(aux[pidx]));
                }
            }
        }
    }
}

// ---------------------------------------------------------------------------
// LRU scan, 3 phases, 2 d-lanes per thread (u32 loads/stores).
// buf_u layout: ((e*BT + b*T + t)*2 + c)*256 + d  (c=0:re, 1:im)
// ---------------------------------------------------------------------------
__global__ __launch_bounds__(256) void scan_a(const u16* __restrict__ u,
    const float* __restrict__ plog, float2* __restrict__ carry)
{
    int l2 = blockIdx.x * 256 + threadIdx.x;      // < 8192
    int chunk = blockIdx.y;
    int dd = (l2 & 127) * 2, b = (l2 >> 7) & 15, e = l2 >> 11;
    float nu0 = expf(plog[e * 256 + dd]),        nu1 = expf(plog[e * 256 + dd + 1]);
    float th0 = expf(plog[1024 + e * 256 + dd]), th1 = expf(plog[1024 + e * 256 + dd + 1]);
    float m0 = expf(-nu0), m1 = expf(-nu1);
    float fr0 = m0 * cosf(th0), fi0 = m0 * sinf(th0);
    float fr1 = m1 * cosf(th1), fi1 = m1 * sinf(th1);
    size_t base = ((size_t)e * BT_ + b * TT) * 512 + (size_t)chunk * CLEN * 512 + dd;
    float hr0 = 0.f, hi0 = 0.f, hr1 = 0.f, hi1 = 0.f;
    for (int t = 0; t < CLEN; t++) {
        unsigned int wr = *reinterpret_cast<const unsigned int*>(u + base);
        unsigned int wi = *reinterpret_cast<const unsigned int*>(u + base + 256);
        float ur0 = b2f((u16)wr), ur1 = b2f((u16)(wr >> 16));
        float ui0 = b2f((u16)wi), ui1 = b2f((u16)(wi >> 16));
        float a0 = fr0 * hr0 - fi0 * hi0 + ur0;
        float b0 = fr0 * hi0 + fi0 * hr0 + ui0;
        float a1 = fr1 * hr1 - fi1 * hi1 + ur1;
        float b1 = fr1 * hi1 + fi1 * hr1 + ui1;
        hr0 = a0; hi0 = b0; hr1 = a1; hi1 = b1;
        base += 512;
    }
    size_t ci = (size_t)chunk * LANES + (size_t)e * 4096 + b * 256 + dd;
    *reinterpret_cast<float4*>(&carry[ci]) = make_float4(hr0, hi0, hr1, hi1);
}

__global__ __launch_bounds__(256) void scan_b(const float* __restrict__ plog,
                                              float2* __restrict__ carry)
{
    int l = blockIdx.x * 256 + threadIdx.x;
    int d = l & 255, e = l >> 12;
    float nu = expf(plog[e * 256 + d]);
    float th = expf(plog[1024 + e * 256 + d]);
    float magL = expf(-nu * (float)CLEN);
    float ang = th * (float)CLEN;
    float frL = magL * cosf(ang), fiL = magL * sinf(ang);
    float gr = 0.f, gi = 0.f;
    for (int j = 0; j < CHUNKS; j++) {
        float2 c = carry[(size_t)j * LANES + l];
        carry[(size_t)j * LANES + l] = make_float2(gr, gi);
        float gr2 = frL * gr - fiL * gi + c.x;
        float gi2 = frL * gi + fiL * gr + c.y;
        gr = gr2; gi = gi2;
    }
}

// scan_c also writes hidden (fp32, exact) on the last chunk.
__global__ __launch_bounds__(256) void scan_c(u16* __restrict__ u,
    const float* __restrict__ plog, const float2* __restrict__ carry,
    float* __restrict__ outh)
{
    int l2 = blockIdx.x * 256 + threadIdx.x;      // < 8192
    int chunk = blockIdx.y;
    int dd = (l2 & 127) * 2, b = (l2 >> 7) & 15, e = l2 >> 11;
    float nu0 = expf(plog[e * 256 + dd]),        nu1 = expf(plog[e * 256 + dd + 1]);
    float th0 = expf(plog[1024 + e * 256 + dd]), th1 = expf(plog[1024 + e * 256 + dd + 1]);
    float m0 = expf(-nu0), m1 = expf(-nu1);
    float fr0 = m0 * cosf(th0), fi0 = m0 * sinf(th0);
    float fr1 = m1 * cosf(th1), fi1 = m1 * sinf(th1);
    size_t base = ((size_t)e * BT_ + b * TT) * 512 + (size_t)chunk * CLEN * 512 + dd;
    size_t ci = (size_t)chunk * LANES + (size_t)e * 4096 + b * 256 + dd;
    float4 c0 = *reinterpret_cast<const float4*>(&carry[ci]);
    float hr0 = c0.x, hi0 = c0.y, hr1 = c0.z, hi1 = c0.w;
    for (int t = 0; t < CLEN; t++) {
        unsigned int wr = *reinterpret_cast<const unsigned int*>(u + base);
        unsigned int wi = *reinterpret_cast<const unsigned int*>(u + base + 256);
        float ur0 = b2f((u16)wr), ur1 = b2f((u16)(wr >> 16));
        float ui0 = b2f((u16)wi), ui1 = b2f((u16)(wi >> 16));
        float a0 = fr0 * hr0 - fi0 * hi0 + ur0;
        float b0 = fr0 * hi0 + fi0 * hr0 + ui0;
        float a1 = fr1 * hr1 - fi1 * hi1 + ur1;
        float b1 = fr1 * hi1 + fi1 * hr1 + ui1;
        hr0 = a0; hi0 = b0; hr1 = a1; hi1 = b1;
        *reinterpret_cast<unsigned int*>(u + base) =
            (unsigned int)f2b(hr0) | ((unsigned int)f2b(hr1) << 16);
        *reinterpret_cast<unsigned int*>(u + base + 256) =
            (unsigned int)f2b(hi0) | ((unsigned int)f2b(hi1) << 16);
        base += 512;
    }
    if (chunk == CHUNKS - 1) {
        float* oh = outh + (size_t)4 * BT_ * 256;
        *reinterpret_cast<float2*>(&oh[b * 2048 + e * 256 + dd])        = make_float2(hr0, hr1);
        *reinterpret_cast<float2*>(&oh[b * 2048 + 1024 + e * 256 + dd]) = make_float2(hi0, hi1);
    }
}

// LayerNorm across (e,d) per row r=(b,t); h2 plain (E, BT, D) bf16; fp32 out
__global__ __launch_bounds__(256) void ln_k(const u16* __restrict__ h2,
    const float* __restrict__ lnw, const float* __restrict__ lnb,
    float* __restrict__ out)
{
    int r = blockIdx.x;
    int d = threadIdx.x;
    float v[4]; float s1 = 0.f, s2 = 0.f;
#pragma unroll
    for (int e = 0; e < 4; e++) {
        float x = b2f(h2[((size_t)e * BT_ + r) * 256 + d]);
        v[e] = x; s1 += x; s2 += x * x;
    }
#pragma unroll
    for (int off = 32; off; off >>= 1) {
        s1 += __shfl_down(s1, off, 64);
        s2 += __shfl_down(s2, off, 64);
    }
    __shared__ float sm[8];
    int wave = threadIdx.x >> 6, lane = threadIdx.x & 63;
    if (lane == 0) { sm[wave] = s1; sm[4 + wave] = s2; }
    __syncthreads();
    float S1 = sm[0] + sm[1] + sm[2] + sm[3];
    float S2 = sm[4] + sm[5] + sm[6] + sm[7];
    float mean = S1 * (1.0f / 1024.0f);
    float var = S2 * (1.0f / 1024.0f) - mean * mean;
    float rstd = rsqrtf(var + 1e-5f);
#pragma unroll
    for (int e = 0; e < 4; e++) {
        float o = (v[e] - mean) * rstd * lnw[e * 256 + d] + lnb[e * 256 + d];
        out[((size_t)e * BT_ + r) * 256 + d] = o;
    }
}

extern "C" void kernel_launch(void* const* d_in, const int* in_sizes, int n_in,
                              void* d_out, int out_size, void* d_ws, size_t ws_size,
                              hipStream_t stream)
{
    const float* x    = (const float*)d_in[0];
    const float* ipw  = (const float*)d_in[1];
    const float* ipb  = (const float*)d_in[2];
    const float* plog = (const float*)d_in[3];
    const float* mw   = (const float*)d_in[4];
    const float* mb   = (const float*)d_in[5];
    const float* fw1  = (const float*)d_in[6];
    const float* fb1  = (const float*)d_in[7];
    const float* fw2  = (const float*)d_in[8];
    const float* fb2  = (const float*)d_in[9];
    const float* lnw  = (const float*)d_in[10];
    const float* lnb  = (const float*)d_in[11];
    float* out = (float*)d_out;

    // Workspace (u16 elem offsets; ~99.5 MiB):
    //   buf_u    [0,          33,554,432)  scan buffer (E,BT,2,D) bf16, later h2
    //   buf_out  [33,554,432, 50,331,648)  mid output bf16; ALIASED early by:
    //              xc (bf16 x, 4,194,304) at 33,554,432   [dead after in_proj]
    //              carry (float2, 4 MiB)  at 37,748,736   [dead after scan_c]
    //   buf_mw_t [50,331,648, 50,855,936)  [e][o][c*256+d] stacked, sign-folded
    //   c_ipw_t  [50,855,936, 51,642,368)  [z][o][i]
    //   c_fw1_t  [51,642,368, 51,904,512)  [e][o][d]
    //   c_fw2_t  [51,904,512, 52,166,656)  [e][o][d]
    // d_out bytes [0, 33.5 MB) double as bf16 scratch for `o` then `h1`.
    u16* W = (u16*)d_ws;
    u16* buf_u    = W;
    u16* buf_out  = W + (size_t)33554432;
    u16* xc       = W + (size_t)33554432;
    float2* carry = (float2*)(W + (size_t)37748736);
    u16* buf_mw_t = W + (size_t)50331648;
    u16* c_ipw_t  = W + (size_t)50855936;
    u16* c_fw1_t  = W + (size_t)51642368;
    u16* c_fw2_t  = W + (size_t)51904512;
    u16* scratch  = (u16*)d_out;

    conv_k<<<16384, 256, 0, stream>>>(x, xc);
    prep_w<<<448, 256, 0, stream>>>(ipw, mw, fw1, fw2, c_ipw_t, buf_mw_t, c_fw1_t, c_fw2_t);
    // in_proj: u0,u1 (gamma-scaled, interleaved) -> buf_u ; o -> d_out scratch
    gemm_k<<<dim3(128, 4, 12), 256, 0, stream>>>(xc, c_ipw_t, ipb, nullptr, plog, buf_u, scratch, 256, 1);
    // LRU scan (chunked, 3 phases), in-place in buf_u (xc dead now); hidden fused into scan_c
    scan_a<<<dim3(32, CHUNKS), 256, 0, stream>>>(buf_u, plog, carry);
    scan_b<<<64, 256, 0, stream>>>(plog, carry);
    scan_c<<<dim3(32, CHUNKS), 256, 0, stream>>>(buf_u, plog, carry, out);
    // mid (K=512 fused r/i) + o -> buf_out   (carry dead now)
    gemm_k<<<dim3(128, 4, 4), 256, 0, stream>>>(buf_u, buf_mw_t, mb, scratch, nullptr, buf_out, nullptr, 512, 2);
    // ff1 + gelu -> d_out scratch (h1; `o` dead)
    gemm_k<<<dim3(128, 4, 4), 256, 0, stream>>>(buf_out, c_fw1_t, fb1, nullptr, nullptr, scratch, nullptr, 256, 3);
    // ff2 + residual -> buf_u (h2 plain; scan data dead)
    gemm_k<<<dim3(128, 4, 4), 256, 0, stream>>>(scratch, c_fw2_t, fb2, buf_out, nullptr, buf_u, nullptr, 256, 4);
    // layernorm across (e,d) -> d_out fp32 (overwrites scratch region last)
    ln_k<<<16384, 256, 0, stream>>>(buf_u, lnw, lnb, out);
}